// Round 8
// baseline (117.419 us; speedup 1.0000x reference)
//
#include <hip/hip_runtime.h>

// ---------------------------------------------------------------------------
// AMM chain, round 8:
//   - precompute re-associated: D2 = {Q=I-VeVe^T, KbT=(s0 K0)@Ke^T,
//     W1T=Ve@V0^T} -- 2048 uniform 64^2 nK=16 blocks, conv-dependent only.
//     (replaces old W0 + serial W0' dispatch)
//   - chain: C1 [betas|betas2]=x@[KbT;K1^T s1] -> z0=betas@W1 (soft) ->
//     ZQ x3 -> ZQF+final.  All chain GEMMs 32x64 tiles, grid 512, 2 blk/CU.
//   - gt32 pipeline deepened: 5 LDS bufs, stage-ahead 3, vmcnt(9/6/3/0).
// fp16 MFMA f32-accum, XOR-swizzled LDS, gload_lds staging throughout.
// ---------------------------------------------------------------------------

typedef _Float16 f16x8 __attribute__((ext_vector_type(8)));
typedef _Float16 f16x4 __attribute__((ext_vector_type(4)));
typedef float f32x4 __attribute__((ext_vector_type(4)));

enum { EPI_H, EPI_QOFF, EPI_SPLIT, EPI_SOFT, EPI_ZQ, EPI_ZQF, EPI_FINAL };

typedef const __attribute__((address_space(1))) void* gas_ptr;
typedef __attribute__((address_space(3))) void* las_ptr;

__device__ __forceinline__ void gload16(const void* g, void* l) {
  __builtin_amdgcn_global_load_lds((gas_ptr)g, (las_ptr)l, 16, 0, 0);
}

__device__ __forceinline__ float softt(float t) {
  float s = fabsf(t) - 1.0f;
  s = s > 0.0f ? s : 0.0f;
  return copysignf(s, t);
}

// ---------------------------------------------------------------------------
// conversions. z=0: transpose+scale keys_t1 -> K1s1T (1024x2048).
// z=1: plain f32->f16 grid-stride over 6 tensors (k0 row-scaled by s0).
// ---------------------------------------------------------------------------
__global__ __launch_bounds__(256) void convAll(
    const float* __restrict__ k1, _Float16* __restrict__ k1s1T,
    const float* __restrict__ s1, const float* __restrict__ x,
    _Float16* __restrict__ x_h, const float* __restrict__ ve,
    _Float16* __restrict__ ve_h, const float* __restrict__ vt1,
    _Float16* __restrict__ vt1_h, const float* __restrict__ k0,
    _Float16* __restrict__ k0s, const float* __restrict__ s0,
    const float* __restrict__ v0, _Float16* __restrict__ v0_h,
    const float* __restrict__ ke, _Float16* __restrict__ ke_h) {
  if (blockIdx.z == 0) {
    __shared__ float t[32][33];
    const int tx = threadIdx.x, ty = threadIdx.y;
    const int c0 = blockIdx.x * 32, r0 = blockIdx.y * 32;
#pragma unroll
    for (int i = 0; i < 32; i += 8)
      t[ty + i][tx] = k1[(size_t)(r0 + ty + i) * 1024 + c0 + tx];
    __syncthreads();
#pragma unroll
    for (int i = 0; i < 32; i += 8) {
      float v = t[tx][ty + i] * s1[c0 + ty + i];
      k1s1T[(size_t)(c0 + ty + i) * 2048 + r0 + tx] = (_Float16)v;
    }
    return;
  }
  const int bid = blockIdx.y * 32 + blockIdx.x;
  const int n_x = 262144, n_ve = 524288, n_v1 = 524288, n_k0 = 262144,
            n_v0 = 262144, n_ke = 524288;
  const int total = n_x + n_ve + n_v1 + n_k0 + n_v0 + n_ke;
  for (int i = bid * 256 + threadIdx.y * 32 + threadIdx.x; i < total;
       i += 2048 * 256) {
    int j = i;
    const float4* s;
    f16x4* d;
    float sc = 1.0f;
    if (j < n_x) {
      s = (const float4*)x; d = (f16x4*)x_h;
    } else if ((j -= n_x) < n_ve) {
      s = (const float4*)ve; d = (f16x4*)ve_h;
    } else if ((j -= n_ve) < n_v1) {
      s = (const float4*)vt1; d = (f16x4*)vt1_h;
    } else if ((j -= n_v1) < n_k0) {
      s = (const float4*)k0; d = (f16x4*)k0s; sc = s0[j >> 8];
    } else if ((j -= n_k0) < n_v0) {
      s = (const float4*)v0; d = (f16x4*)v0_h;
    } else {
      j -= n_v0; s = (const float4*)ke; d = (f16x4*)ke_h;
    }
    float4 v = s[j];
    f16x4 h = {(_Float16)(v.x * sc), (_Float16)(v.y * sc),
               (_Float16)(v.z * sc), (_Float16)(v.w * sc)};
    d[j] = h;
  }
}

// ---------------------------------------------------------------------------
// 64x64 tile, NT, 4 waves (wr=M-half, wk=K-half), wave tile 32x64.
// gload_lds 4+4 bufs, ahead 2, vmcnt(8/4/0), 1 barrier/K-step. [R6/R7-proven]
// ---------------------------------------------------------------------------
template <int EPI>
__device__ __forceinline__ void gtile(
    const _Float16* __restrict__ A, int lda, const _Float16* __restrict__ B,
    int ldb, int nK, int N, int brow, int bcol, float* __restrict__ dgout,
    _Float16* __restrict__ oh, _Float16* sm, int tid) {
  const int lane = tid & 63;
  const int w = tid >> 6;
  const int wr = w & 1;
  const int wk = w >> 1;
  const int srow = lane >> 3;
  const int scol = ((lane & 7) ^ srow) << 3;
  const int a15 = lane & 15;
  const int hi = lane >> 4;
  const int l7 = lane & 7;

  const _Float16* apg = A + (size_t)(brow + (w << 4) + srow) * lda + scol;
  const _Float16* bpg = B + (size_t)(bcol + (w << 4) + srow) * ldb + scol;
  _Float16* AB = sm;
  _Float16* BB = sm + 16384;
  const int ldstA = w << 10;

  const int ca = ((wk << 2) + hi) ^ l7;
  int raddr[2], baddr[4];
#pragma unroll
  for (int mi = 0; mi < 2; ++mi)
    raddr[mi] = ((wr << 5) + (mi << 4) + a15) * 64 + (ca << 3);
#pragma unroll
  for (int ni = 0; ni < 4; ++ni)
    baddr[ni] = ((ni << 4) + a15) * 64 + (ca << 3);

  f32x4 acc[2][4] = {};

  __syncthreads();

#pragma unroll
  for (int p = 0; p < 2; ++p) {
    gload16(apg + p * 64, AB + p * 4096 + ldstA);
    gload16(apg + p * 64 + (size_t)8 * lda, AB + p * 4096 + ldstA + 512);
    gload16(bpg + p * 64, BB + p * 4096 + ldstA);
    gload16(bpg + p * 64 + (size_t)8 * ldb, BB + p * 4096 + ldstA + 512);
  }

  for (int kt = 0; kt < nK; ++kt) {
    if (kt + 2 < nK) {
      const int bf = (kt + 2) & 3;
      const int co = (kt + 2) << 6;
      gload16(apg + co, AB + bf * 4096 + ldstA);
      gload16(apg + co + (size_t)8 * lda, AB + bf * 4096 + ldstA + 512);
      gload16(bpg + co, BB + bf * 4096 + ldstA);
      gload16(bpg + co + (size_t)8 * ldb, BB + bf * 4096 + ldstA + 512);
    }
    const int rem = nK - 1 - kt;
    if (rem >= 2)
      asm volatile("s_waitcnt vmcnt(8)" ::: "memory");
    else if (rem == 1)
      asm volatile("s_waitcnt vmcnt(4)" ::: "memory");
    else
      asm volatile("s_waitcnt vmcnt(0)" ::: "memory");
    __builtin_amdgcn_s_barrier();
    __builtin_amdgcn_sched_barrier(0);
    const _Float16* Ab = AB + (kt & 3) * 4096;
    const _Float16* Bb = BB + (kt & 3) * 4096;
    f16x8 av[2], bv[4];
    av[0] = *(const f16x8*)(Ab + raddr[0]);
    av[1] = *(const f16x8*)(Ab + raddr[1]);
    bv[0] = *(const f16x8*)(Bb + baddr[0]);
    bv[1] = *(const f16x8*)(Bb + baddr[1]);
    bv[2] = *(const f16x8*)(Bb + baddr[2]);
    bv[3] = *(const f16x8*)(Bb + baddr[3]);
#pragma unroll
    for (int mi = 0; mi < 2; ++mi)
#pragma unroll
      for (int ni = 0; ni < 4; ++ni)
        acc[mi][ni] = __builtin_amdgcn_mfma_f32_16x16x32_f16(
            av[mi], bv[ni], acc[mi][ni], 0, 0, 0);
  }

  __syncthreads();
  float* scr = (float*)sm;
  const int sl = (wr << 6) + lane;
  if (wk == 1) {
#pragma unroll
    for (int mi = 0; mi < 2; ++mi)
#pragma unroll
      for (int ni = 0; ni < 4; ++ni)
#pragma unroll
        for (int r = 0; r < 4; ++r)
          scr[(((mi << 2) + ni) * 4 + r) * 128 + sl] = acc[mi][ni][r];
  }
  __syncthreads();
  if (wk == 0) {
#pragma unroll
    for (int mi = 0; mi < 2; ++mi) {
#pragma unroll
      for (int ni = 0; ni < 4; ++ni) {
#pragma unroll
        for (int r = 0; r < 4; ++r) {
          const float v =
              acc[mi][ni][r] + scr[(((mi << 2) + ni) * 4 + r) * 128 + sl];
          const int row = brow + (wr << 5) + (mi << 4) + (hi << 2) + r;
          const int col = bcol + (ni << 4) + a15;
          const size_t idx = (size_t)row * N + col;
          if constexpr (EPI == EPI_H) {
            oh[idx] = (_Float16)v;
          } else {  // EPI_QOFF
            if (row == col) {
              dgout[row] = 1.0f - v;
              oh[idx] = (_Float16)0.0f;
            } else {
              oh[idx] = (_Float16)(-v);
            }
          }
        }
      }
    }
  }
}

// ---------------------------------------------------------------------------
// 32x64 tile, NT, 4 waves (wc=N-half, wk=K-half), wave tile 32x32.
// grid 512 for M=512/N=2048 -> 2 blocks/CU. LDS 60 KB: A 5x4KB + B 5x8KB.
// 3 gloads/wave/step, stage-ahead 3 (5 bufs), vmcnt(9/6/3/0), 1 barrier/step.
// ---------------------------------------------------------------------------
template <int EPI>
__device__ __forceinline__ void gt32(
    const _Float16* __restrict__ A, int lda, const _Float16* __restrict__ B,
    int ldb, int nK, int N, int brow, int bcol, const float* __restrict__ dgv,
    float* __restrict__ fA, float* __restrict__ fB,
    _Float16* __restrict__ oh, _Float16* __restrict__ oh2,
    float* __restrict__ ofin, _Float16* sm, int tid) {
  const int lane = tid & 63;
  const int w = tid >> 6;
  const int wc = w & 1;   // N half (32 cols)
  const int wk = w >> 1;  // K half within 64-step
  const int srow = lane >> 3;
  const int scol = ((lane & 7) ^ srow) << 3;
  const int a15 = lane & 15, hi = lane >> 4, l7 = lane & 7;

  const _Float16* apg = A + (size_t)(brow + (w << 3) + srow) * lda + scol;
  const _Float16* bpg = B + (size_t)(bcol + (w << 4) + srow) * ldb + scol;
  _Float16* AB = sm;           // 5 bufs x 2048 halfs
  _Float16* BB = sm + 10240;   // 5 bufs x 4096 halfs
  const int ca = ((wk << 2) + hi) ^ l7;
  int raddr[2], baddr[2];
#pragma unroll
  for (int mi = 0; mi < 2; ++mi)
    raddr[mi] = ((mi << 4) + a15) * 64 + (ca << 3);
#pragma unroll
  for (int ni = 0; ni < 2; ++ni)
    baddr[ni] = ((wc << 5) + (ni << 4) + a15) * 64 + (ca << 3);

  f32x4 acc[2][2] = {};
  __syncthreads();  // LDS handoff

#pragma unroll
  for (int p = 0; p < 3; ++p) {
    gload16(apg + p * 64, AB + p * 2048 + (w << 9));
    gload16(bpg + p * 64, BB + p * 4096 + (w << 10));
    gload16(bpg + p * 64 + (size_t)8 * ldb, BB + p * 4096 + (w << 10) + 512);
  }
  int bi = 0, bs = 3;
  for (int kt = 0; kt < nK; ++kt) {
    if (kt + 3 < nK) {
      const int co = (kt + 3) << 6;
      gload16(apg + co, AB + bs * 2048 + (w << 9));
      gload16(bpg + co, BB + bs * 4096 + (w << 10));
      gload16(bpg + co + (size_t)8 * ldb, BB + bs * 4096 + (w << 10) + 512);
    }
    const int rem = nK - 1 - kt;
    if (rem >= 3)
      asm volatile("s_waitcnt vmcnt(9)" ::: "memory");
    else if (rem == 2)
      asm volatile("s_waitcnt vmcnt(6)" ::: "memory");
    else if (rem == 1)
      asm volatile("s_waitcnt vmcnt(3)" ::: "memory");
    else
      asm volatile("s_waitcnt vmcnt(0)" ::: "memory");
    __builtin_amdgcn_s_barrier();
    __builtin_amdgcn_sched_barrier(0);
    const _Float16* Ab = AB + bi * 2048;
    const _Float16* Bb = BB + bi * 4096;
    f16x8 av[2], bv[2];
    av[0] = *(const f16x8*)(Ab + raddr[0]);
    av[1] = *(const f16x8*)(Ab + raddr[1]);
    bv[0] = *(const f16x8*)(Bb + baddr[0]);
    bv[1] = *(const f16x8*)(Bb + baddr[1]);
#pragma unroll
    for (int mi = 0; mi < 2; ++mi)
#pragma unroll
      for (int ni = 0; ni < 2; ++ni)
        acc[mi][ni] = __builtin_amdgcn_mfma_f32_16x16x32_f16(
            av[mi], bv[ni], acc[mi][ni], 0, 0, 0);
    bi = bi == 4 ? 0 : bi + 1;
    bs = bs == 4 ? 0 : bs + 1;
  }
  __syncthreads();
  float* scr = (float*)sm;
  const int sl = (wc << 6) + lane;
  if (wk == 1) {
#pragma unroll
    for (int mi = 0; mi < 2; ++mi)
#pragma unroll
      for (int ni = 0; ni < 2; ++ni)
#pragma unroll
        for (int r = 0; r < 4; ++r)
          scr[(((mi << 1) + ni) * 4 + r) * 128 + sl] = acc[mi][ni][r];
  }
  __syncthreads();
  if (wk == 0) {
#pragma unroll
    for (int mi = 0; mi < 2; ++mi) {
#pragma unroll
      for (int ni = 0; ni < 2; ++ni) {
#pragma unroll
        for (int r = 0; r < 4; ++r) {
          const float v =
              acc[mi][ni][r] + scr[(((mi << 1) + ni) * 4 + r) * 128 + sl];
          const int row = brow + (mi << 4) + (hi << 2) + r;
          const int col = bcol + (wc << 5) + (ni << 4) + a15;
          const size_t idx = (size_t)row * N + col;
          if constexpr (EPI == EPI_SPLIT) {
            if (col < 1024)
              oh[(size_t)row * 1024 + col] = (_Float16)v;
            else
              oh2[(size_t)row * 1024 + (col - 1024)] = (_Float16)v;
          } else if constexpr (EPI == EPI_SOFT) {
            fA[idx] = v;
            float s = softt(v);
            fB[idx] = s;
            oh[idx] = (_Float16)s;
          } else if constexpr (EPI == EPI_ZQ) {
            float t = fA[idx] + dgv[col] * fB[idx] + v;
            float s = softt(t);
            fB[idx] = s;
            oh[idx] = (_Float16)s;
          } else if constexpr (EPI == EPI_ZQF) {
            float t = fA[idx] + dgv[col] * fB[idx] + v;
            fB[idx] = softt(t);
          } else {  // EPI_FINAL
            ofin[idx] = fB[idx] + v;
          }
        }
      }
    }
  }
}

// ---------------------------------------------------------------------------
struct WS {
  const _Float16 *ve, *vt1, *w1T_r, *Bcat, *qoff_r, *x, *k0s, *v0, *ke,
      *bet_r, *be2_r;
  _Float16 *w1T_w, *KbT_w, *qoff_w, *bet_w, *be2_w, *zhA, *zhB;
  float *z0, *zf, *dg;
};

// 512-block XCD-chunked map for 16(brow32) x 32(bcol64) tiles
__device__ __forceinline__ void map512(int b, int& br, int& bc) {
  const int x = b & 7, i = b >> 3;
  bc = (x << 2) | (i & 3);  // 0..31
  br = i >> 2;              // 0..15
}

// D2: 2048 uniform blocks (nK=16): [0,1024) Q | [1024,1536) KbT | rest W1T
__global__ __launch_bounds__(256, 2) void kD2(WS p) {
  __shared__ __align__(16) _Float16 sm[32768];
  const int tid = threadIdx.x;
  const int bid = blockIdx.x;
  if (bid < 1024) {  // Q = I - Ve Ve^T (2048x2048, K=1024)
    gtile<EPI_QOFF>(p.ve, 1024, p.ve, 1024, 16, 2048, (bid >> 5) << 6,
                    (bid & 31) << 6, p.dg, p.qoff_w, sm, tid);
  } else if (bid < 1536) {  // KbT = (s0 K0) @ Ke^T (1024x2048, K=1024)
    const int i = bid - 1024;
    gtile<EPI_H>(p.k0s, 1024, p.ke, 1024, 16, 2048, (i >> 5) << 6,
                 (i & 31) << 6, nullptr, p.KbT_w, sm, tid);
  } else {  // W1T = Ve @ V0^T (2048x1024, K=1024)
    const int i = bid - 1536;
    gtile<EPI_H>(p.ve, 1024, p.v0, 1024, 16, 1024, (i >> 4) << 6,
                 (i & 15) << 6, nullptr, p.w1T_w, sm, tid);
  }
}

// C1: [betas | betas2] = x @ [KbT ; K1^T s1]  (512x2048, K=2048)
__global__ __launch_bounds__(256, 2) void kC1(WS p) {
  __shared__ __align__(16) _Float16 sm[30720];
  int br, bc;
  map512(blockIdx.x, br, bc);
  gt32<EPI_SPLIT>(p.x, 2048, p.Bcat, 2048, 32, 2048, br << 5, bc << 6,
                  nullptr, nullptr, nullptr, p.bet_w, p.be2_w, nullptr, sm,
                  threadIdx.x);
}

// z0 = betas @ W1 (soft fused) (512x2048, K=1024)
__global__ __launch_bounds__(256, 2) void kC2(WS p) {
  __shared__ __align__(16) _Float16 sm[30720];
  int br, bc;
  map512(blockIdx.x, br, bc);
  gt32<EPI_SOFT>(p.bet_r, 1024, p.w1T_r, 1024, 16, 2048, br << 5, bc << 6,
                 nullptr, p.z0, p.zf, p.zhA, nullptr, nullptr, sm,
                 threadIdx.x);
}

template <bool AB>
__global__ __launch_bounds__(256, 2) void kZQ(WS p) {
  __shared__ __align__(16) _Float16 sm[30720];
  int br, bc;
  map512(blockIdx.x, br, bc);  // z = soft(z0 + dg*z + z@Qoff)
  gt32<EPI_ZQ>(AB ? p.zhA : p.zhB, 2048, p.qoff_r, 2048, 32, 2048, br << 5,
               bc << 6, p.dg, p.z0, p.zf, AB ? p.zhB : p.zhA, nullptr,
               nullptr, sm, threadIdx.x);
}

__global__ __launch_bounds__(256, 2) void kZQF(WS p, float* out) {
  __shared__ __align__(16) _Float16 sm[30720];
  int br, bc;
  map512(blockIdx.x, br, bc);  // last ZQ (zf only) + final y
  gt32<EPI_ZQF>(p.zhB, 2048, p.qoff_r, 2048, 32, 2048, br << 5, bc << 6, p.dg,
                p.z0, p.zf, nullptr, nullptr, nullptr, sm, threadIdx.x);
  gt32<EPI_FINAL>(p.be2_r, 1024, p.vt1, 1024, 16, 2048, br << 5, bc << 6,
                  nullptr, nullptr, p.zf, nullptr, nullptr, out, sm,
                  threadIdx.x);
}

// ---------------------------------------------------------------------------
extern "C" void kernel_launch(void* const* d_in, const int* in_sizes, int n_in,
                              void* d_out, int out_size, void* d_ws,
                              size_t ws_size, hipStream_t stream) {
  const float* x = (const float*)d_in[0];          // (512,2048)
  const float* key_enc = (const float*)d_in[1];    // (2048,1024)
  const float* val_enc = (const float*)d_in[2];    // (2048,1024)
  const float* keys_t0 = (const float*)d_in[3];    // (1024,1024)
  const float* vals_t0 = (const float*)d_in[4];    // (1024,1024)
  const float* scales_t0 = (const float*)d_in[5];  // (1024,)
  const float* keys_t1 = (const float*)d_in[6];    // (2048,1024)
  const float* vals_t1 = (const float*)d_in[7];    // (2048,1024)
  const float* scales_t1 = (const float*)d_in[8];  // (1024,)

  // workspace (half offsets; 1M = 1048576), lifetime-overlaid, ~40 MB
  constexpr size_t M1 = 1048576;
  _Float16* ws = (_Float16*)d_ws;
  _Float16* ve_h = ws;                    // [0,2M) conv; dead after D2
  float* z_f = (float*)ws;                //   overlay (D4+): 1M f32
  _Float16* vt1_h = ws + 2 * M1;          // [2M,4M) conv; read D8
  _Float16* w1T = ws + 4 * M1;            // [4M,6M) D2 out; D4 B
  _Float16* Bcat = ws + 6 * M1;           // [6M,10M): KbT | K1s1T; dead @D3
  _Float16* zhA = ws + 6 * M1;            //   overlay (D4+)
  _Float16* zhB = ws + 7 * M1;            //   overlay (D4+)
  float* z0_f = (float*)(ws + 8 * M1);    //   overlay (D4+): 1M f32
  _Float16* ke_h = ws + 10 * M1;          // [10M,12M) conv; D2 B (KbT)
  _Float16* x_h = ws + 12 * M1;           // [12M,13M) conv; D3 A
  _Float16* k0s = ws + 13 * M1;           // [13M,14M) conv; D2 A; dead @D2
  _Float16* bet_h = ws + 13 * M1;         //   overlay (D3+): 0.5M
  _Float16* be2_h = ws + 13 * M1 + 524288;  // overlay (D3+): 0.5M
  _Float16* v0_h = ws + 14 * M1;          // [14M,15M) conv; D2 B (W1T)
  float* dg = (float*)(ws + 15 * M1);     // [15M,+4K) D2 out
  _Float16* qoff = ws + 16 * M1;          // [16M,20M) D2 out; D5-D8

  WS p;
  p.ve = ve_h; p.vt1 = vt1_h; p.w1T_r = w1T; p.w1T_w = w1T;
  p.Bcat = Bcat; p.KbT_w = Bcat; p.qoff_r = qoff; p.qoff_w = qoff;
  p.x = x_h; p.k0s = k0s; p.v0 = v0_h; p.ke = ke_h;
  p.bet_r = bet_h; p.bet_w = bet_h; p.be2_r = be2_h; p.be2_w = be2_h;
  p.zhA = zhA; p.zhB = zhB; p.z0 = z0_f; p.zf = z_f; p.dg = dg;

  // D1: conversions (K1s1T goes to Bcat rows 1024..2047)
  convAll<<<dim3(32, 64, 2), dim3(32, 8), 0, stream>>>(
      keys_t1, Bcat + 2 * M1, scales_t1, x, x_h, val_enc, ve_h, vals_t1,
      vt1_h, keys_t0, k0s, scales_t0, vals_t0, v0_h, key_enc, ke_h);
  // D2: Q || KbT || W1T (2048 uniform blocks)
  kD2<<<2048, 256, 0, stream>>>(p);
  // D3: C1 [betas|betas2]
  kC1<<<512, 256, 0, stream>>>(p);
  // D4: z0 = betas @ W1 (soft) -> z0_f, z_f, zhA
  kC2<<<512, 256, 0, stream>>>(p);
  // D5-D7: ISTA iters 2..4 (zh ping-pong)
  kZQ<true><<<512, 256, 0, stream>>>(p);   // zhA -> zhB
  kZQ<false><<<512, 256, 0, stream>>>(p);  // zhB -> zhA
  kZQ<true><<<512, 256, 0, stream>>>(p);   // zhA -> zhB
  // D8: ISTA iter 5 (zf only) + final y = z + betas2 @ V1^T
  kZQF<<<512, 256, 0, stream>>>(p, (float*)d_out);
}